// Round 6
// baseline (490.926 us; speedup 1.0000x reference)
//
#include <hip/hip_runtime.h>
#include <hip/hip_bf16.h>

#define D_ 768
#define E_ 8
#define H_ 3072
#define N_TOK 4096
#define BM 128
#define BN 128
#define BK 64

typedef _Float16 f16;
typedef f16 f16x8 __attribute__((ext_vector_type(8)));
typedef float f32x4 __attribute__((ext_vector_type(4)));

// ---------------- weight convert + transpose: fp32 [R][C] -> fp16 [C][R] ----------------
#define TP 66
__global__ __launch_bounds__(256) void cvt_w_t(const float* __restrict__ in,
                                               f16* __restrict__ outp,
                                               int R, int C) {
    __shared__ f16 t[64][TP];
    const float* src = in + (size_t)blockIdx.z * R * C;
    f16* dst = outp + (size_t)blockIdx.z * R * C;
    int r0 = blockIdx.y * 64, c0 = blockIdx.x * 64;
    int tid = threadIdx.x;
    {
        int r = tid >> 4;
        int c = (tid & 15) * 4;
#pragma unroll
        for (int i = 0; i < 4; i++) {
            float4 v = *(const float4*)(src + (size_t)(r0 + r + i * 16) * C + (c0 + c));
            t[r + i * 16][c] = (f16)v.x;
            t[r + i * 16][c + 1] = (f16)v.y;
            t[r + i * 16][c + 2] = (f16)v.z;
            t[r + i * 16][c + 3] = (f16)v.w;
        }
    }
    __syncthreads();
    {
        int c = tid >> 3;
        int rr = (tid & 7) * 8;
#pragma unroll
        for (int i = 0; i < 2; i++) {
            int cc = c + i * 32;
            f16x8 o;
#pragma unroll
            for (int j = 0; j < 8; j++) o[j] = t[rr + j][cc];
            *(f16x8*)(dst + (size_t)(c0 + cc) * R + (r0 + rr)) = o;
        }
    }
}

// ---------------- router ----------------
__global__ __launch_bounds__(256) void router(const float* __restrict__ x,
                                              const float* __restrict__ gw,
                                              const float* __restrict__ gb,
                                              int* __restrict__ counts,
                                              int* __restrict__ list,
                                              float* __restrict__ wslot) {
    int wv = threadIdx.x >> 6;
    int lane = threadIdx.x & 63;
    int tok = blockIdx.x * 4 + wv;
    const float* xr = x + (size_t)tok * D_;
    float acc[E_];
#pragma unroll
    for (int e = 0; e < E_; e++) acc[e] = 0.f;
    for (int d = lane; d < D_; d += 64) {
        float v = xr[d];
        const float* g = gw + d * E_;
#pragma unroll
        for (int e = 0; e < E_; e++) acc[e] += v * g[e];
    }
#pragma unroll
    for (int e = 0; e < E_; e++) {
#pragma unroll
        for (int off = 32; off; off >>= 1) acc[e] += __shfl_xor(acc[e], off, 64);
    }
    if (lane == 0) {
        float v0 = -3.4e38f, v1 = -3.4e38f;
        int i0 = 0, i1 = 0;
#pragma unroll
        for (int e = 0; e < E_; e++) {
            float l = acc[e] + gb[e];
            if (l > v0) { v1 = v0; i1 = i0; v0 = l; i0 = e; }
            else if (l > v1) { v1 = l; i1 = e; }
        }
        float p1 = expf(v1 - v0);
        float s = 1.f + p1;
        int p0 = atomicAdd(&counts[i0], 1);
        list[i0 * N_TOK + p0] = tok * 2;
        int p1p = atomicAdd(&counts[i1], 1);
        list[i1 * N_TOK + p1p] = tok * 2 + 1;
        wslot[tok * 2] = 1.f / s;
        wslot[tok * 2 + 1] = p1 / s;
    }
}

// ---------------- prefix scan over 8 counts ----------------
__global__ void scan8(const int* __restrict__ counts, int* __restrict__ offs) {
    if (threadIdx.x == 0) {
        int s = 0;
#pragma unroll
        for (int e = 0; e < E_; e++) { offs[e] = s; s += counts[e]; }
        offs[E_] = s;
    }
}

// ---------------- pack A: gather token rows -> packed fp16 [8192][D] ----------------
__global__ __launch_bounds__(256) void pack_a(const float* __restrict__ x,
                                              const int* __restrict__ counts,
                                              const int* __restrict__ offs,
                                              const int* __restrict__ list,
                                              f16* __restrict__ xg) {
    int wv = threadIdx.x >> 6, lane = threadIdx.x & 63;
    int idx = blockIdx.x * 4 + wv;            // e*N_TOK + j
    int e = idx >> 12, j = idx & (N_TOK - 1);
    if (j >= counts[e]) return;
    int id = list[idx];
    const float* xr = x + (size_t)(id >> 1) * D_;
    f16* dst = xg + (size_t)(offs[e] + j) * D_;
#pragma unroll
    for (int c = 0; c < 3; c++) {
        float4 v = *(const float4*)(xr + lane * 4 + c * 256);
        f16 o[4] = {(f16)v.x, (f16)v.y, (f16)v.z, (f16)v.w};
        *(float2*)(dst + lane * 4 + c * 256) = *(const float2*)o;
    }
}

// ---------------- shared GEMM machinery ----------------
#define LOADS(SA, SB, kk) do {                                              \
    _Pragma("unroll")                                                       \
    for (int j = 0; j < 4; j++) {                                           \
        SA[j] = *(const f16x8*)(aptr + (kk) + j * 8);                       \
        SB[j] = *(const f16x8*)(bptr + (kk) + j * 8);                       \
    }                                                                       \
} while (0)

#define WRITES(SA, SB) do {                                                 \
    _Pragma("unroll")                                                       \
    for (int j = 0; j < 4; j++) {                                           \
        *(f16x8*)(ldsb + lbA[j]) = SA[j];                                   \
        *(f16x8*)(ldsb + lbB[j]) = SB[j];                                   \
    }                                                                       \
} while (0)

#define COMPUTE() do {                                                      \
    _Pragma("unroll")                                                       \
    for (int ks = 0; ks < 2; ks++) {                                        \
        f16x8 af[4], bf[4];                                                 \
        _Pragma("unroll")                                                   \
        for (int m = 0; m < 4; m++)                                         \
            af[m] = *(const f16x8*)(ldsb + (wr + m * 16 + fr) * 128 +       \
                                    ((ks * 4 + qh) ^ (fr & 7)) * 16);       \
        _Pragma("unroll")                                                   \
        for (int n = 0; n < 4; n++)                                         \
            bf[n] = *(const f16x8*)(ldsb + 16384 + (wc + n * 16 + fr) * 128 + \
                                    ((ks * 4 + qh) ^ (fr & 7)) * 16);       \
        _Pragma("unroll")                                                   \
        for (int m = 0; m < 4; m++)                                         \
            _Pragma("unroll")                                               \
            for (int n = 0; n < 4; n++)                                     \
                acc[m][n] = __builtin_amdgcn_mfma_f32_16x16x32_f16(af[m], bf[n], acc[m][n], 0, 0, 0); \
    }                                                                       \
} while (0)

#define GEMM_MAIN(NT) do {                                                  \
    LOADS(S0A, S0B, 0);                                                     \
    WRITES(S0A, S0B);                                                       \
    LOADS(S1A, S1B, BK);                                                    \
    __syncthreads();                                                        \
    _Pragma("unroll 1")                                                     \
    for (int t = 0; t < (NT); t += 2) {                                     \
        if (t + 2 < (NT)) LOADS(S0A, S0B, (t + 2) * BK);                    \
        COMPUTE();                                                          \
        __syncthreads();                                                    \
        WRITES(S1A, S1B);                                                   \
        __syncthreads();                                                    \
        if (t + 3 < (NT)) LOADS(S1A, S1B, (t + 3) * BK);                    \
        COMPUTE();                                                          \
        __syncthreads();                                                    \
        if (t + 2 < (NT)) WRITES(S0A, S0B);                                 \
        __syncthreads();                                                    \
    }                                                                       \
} while (0)

// ---------------- GEMM1: h = gelu(xg @ w1 + b1), dense packed ----------------
__global__ __launch_bounds__(256) void gemm1(const f16* __restrict__ xg,
                                             const f16* __restrict__ w1t,
                                             const float* __restrict__ b1,
                                             const int* __restrict__ counts,
                                             const int* __restrict__ offs,
                                             f16* __restrict__ hbuf) {
    int bid = blockIdx.x;
    int e = bid & 7;
    int within = bid >> 3;
    int xb = within % (H_ / BN);       // fastest: shares A panel across N-tiles
    int yb = within / (H_ / BN);
    int cnt = counts[e];
    int off = offs[e];
    int rb = yb * BM;
    if (rb >= cnt) return;
    int cb = xb * BN;

    __shared__ f16 AB[2][BM][BK];      // A @0, B @16384; XOR-swizzled 16B chunks
    char* ldsb = (char*)&AB[0][0][0];

    int tid = threadIdx.x;
    int wv = tid >> 6, lane = tid & 63;

    int ar = tid & 127;
    int kh = tid >> 7;
    int arow = off + rb + ar; if (arow > E_ * N_TOK / 4 * 4 - 1) arow = E_ * N_TOK / 4 * 4 - 1;
    if (arow > 8191) arow = 8191;
    const f16* aptr = xg + (size_t)arow * D_ + kh * 32;
    const f16* bptr = w1t + (size_t)e * H_ * D_ + (size_t)(cb + ar) * D_ + kh * 32;
    unsigned lbA[4], lbB[4];
#pragma unroll
    for (int j = 0; j < 4; j++) {
        unsigned c = (unsigned)((kh * 4 + j) ^ (ar & 7));
        lbA[j] = (unsigned)(ar * 128) + c * 16;
        lbB[j] = 16384u + (unsigned)(ar * 128) + c * 16;
    }

    int wr = (wv >> 1) * 64, wc = (wv & 1) * 64;
    int fr = lane & 15, qh = lane >> 4;

    f32x4 acc[4][4] = {};
    f16x8 S0A[4], S0B[4], S1A[4], S1B[4];

    GEMM_MAIN(D_ / BK);   // 12

#pragma unroll
    for (int n = 0; n < 4; n++) {
        int colg = cb + wc + n * 16 + fr;
        float bias = b1[e * H_ + colg];
#pragma unroll
        for (int m = 0; m < 4; m++) {
#pragma unroll
            for (int r = 0; r < 4; r++) {
                int j = rb + wr + m * 16 + qh * 4 + r;
                if (j < cnt) {
                    float v = acc[m][n][r] + bias;
                    v = 0.5f * v * (1.f + erff(v * 0.70710678f));
                    hbuf[(size_t)(off + j) * H_ + colg] = (f16)v;
                }
            }
        }
    }
}

// ---------------- GEMM2: y = (hbuf @ w2 + b2) * wslot, scatter-add ----------------
#define KSPLIT 2
#define KCH (H_ / KSPLIT)
__global__ __launch_bounds__(256) void gemm2(const f16* __restrict__ hbuf,
                                             const f16* __restrict__ w2t,
                                             const float* __restrict__ b2,
                                             const int* __restrict__ counts,
                                             const int* __restrict__ offs,
                                             const int* __restrict__ list,
                                             const float* __restrict__ wslot,
                                             float* __restrict__ out) {
    int bid = blockIdx.x;
    int e = bid & 7;
    int within = bid >> 3;
    int xk = within % ((D_ / BN) * KSPLIT);   // 12, fastest
    int yb = within / ((D_ / BN) * KSPLIT);
    int cnt = counts[e];
    int off = offs[e];
    int rb = yb * BM;
    if (rb >= cnt) return;
    int cb = (xk % (D_ / BN)) * BN;
    int kz = xk / (D_ / BN);
    int k0 = kz * KCH;

    __shared__ f16 AB[2][BM][BK];
    char* ldsb = (char*)&AB[0][0][0];

    int tid = threadIdx.x;
    int wv = tid >> 6, lane = tid & 63;

    int ar = tid & 127;
    int kh = tid >> 7;
    int arow = off + rb + ar;
    if (arow > 8191) arow = 8191;
    const f16* aptr = hbuf + (size_t)arow * H_ + k0 + kh * 32;
    const f16* bptr = w2t + (size_t)e * D_ * H_ + (size_t)(cb + ar) * H_ + k0 + kh * 32;
    unsigned lbA[4], lbB[4];
#pragma unroll
    for (int j = 0; j < 4; j++) {
        unsigned c = (unsigned)((kh * 4 + j) ^ (ar & 7));
        lbA[j] = (unsigned)(ar * 128) + c * 16;
        lbB[j] = 16384u + (unsigned)(ar * 128) + c * 16;
    }

    int wr = (wv >> 1) * 64, wc = (wv & 1) * 64;
    int fr = lane & 15, qh = lane >> 4;

    f32x4 acc[4][4] = {};
    f16x8 S0A[4], S0B[4], S1A[4], S1B[4];

    GEMM_MAIN(KCH / BK);   // 24

#pragma unroll
    for (int n = 0; n < 4; n++) {
        int colg = cb + wc + n * 16 + fr;
        float bias = (kz == 0) ? b2[e * D_ + colg] : 0.f;
#pragma unroll
        for (int m = 0; m < 4; m++) {
#pragma unroll
            for (int r = 0; r < 4; r++) {
                int j = rb + wr + m * 16 + qh * 4 + r;
                if (j < cnt) {
                    int id = list[e * N_TOK + j];
                    float w = wslot[id];
                    float v = (acc[m][n][r] + bias) * w;
                    atomicAdd(&out[(size_t)(id >> 1) * D_ + colg], v);
                }
            }
        }
    }
}

extern "C" void kernel_launch(void* const* d_in, const int* in_sizes, int n_in,
                              void* d_out, int out_size, void* d_ws, size_t ws_size,
                              hipStream_t stream) {
    const float* x = (const float*)d_in[0];
    const float* gate_w = (const float*)d_in[1];
    const float* gate_b = (const float*)d_in[2];
    const float* w1 = (const float*)d_in[3];
    const float* b1 = (const float*)d_in[4];
    const float* w2 = (const float*)d_in[5];
    const float* b2 = (const float*)d_in[6];
    float* out = (float*)d_out;

    char* ws = (char*)d_ws;
    int* counts = (int*)ws;                           // 32 B
    int* offs = (int*)(ws + 256);                     // 36 B
    int* list = (int*)(ws + 1024);                    // 131072 B
    float* wslot = (float*)(ws + 132096);             // 32768 B
    f16* xg = (f16*)(ws + 196608);                    // 8192*768*2  = 12582912 B
    f16* w1t = (f16*)(ws + 12779520);                 // 37748736 B
    f16* w2t = (f16*)(ws + 50528256);                 // 37748736 B
    f16* hbuf = (f16*)(ws + 88276992);                // 8192*3072*2 = 50331648 B (end ~132.2 MiB)

    hipMemsetAsync(counts, 0, 256, stream);
    hipMemsetAsync(out, 0, (size_t)out_size * sizeof(float), stream);

    router<<<1024, 256, 0, stream>>>(x, gate_w, gate_b, counts, list, wslot);
    scan8<<<1, 64, 0, stream>>>(counts, offs);
    pack_a<<<E_ * N_TOK / 4, 256, 0, stream>>>(x, counts, offs, list, xg);
    cvt_w_t<<<dim3(H_ / 64, D_ / 64, E_), 256, 0, stream>>>(w1, w1t, D_, H_);
    cvt_w_t<<<dim3(D_ / 64, H_ / 64, E_), 256, 0, stream>>>(w2, w2t, H_, D_);
    gemm1<<<(H_ / BN) * (N_TOK / BM) * E_, 256, 0, stream>>>(xg, w1t, b1, counts, offs, hbuf);
    gemm2<<<(D_ / BN) * KSPLIT * (N_TOK / BM) * E_, 256, 0, stream>>>(hbuf, w2t, b2, counts, offs, list, wslot, out);
}

// Round 7
// 434.634 us; speedup vs baseline: 1.1295x; 1.1295x over previous
//
#include <hip/hip_runtime.h>
#include <hip/hip_bf16.h>

#define D_ 768
#define E_ 8
#define H_ 3072
#define N_TOK 4096
#define BM 128
#define BN 128
#define BK 32
#define PADK 40   // 32 + 8 halfs: 80B row stride breaks bank aliasing, 16B aligned

typedef _Float16 f16;
typedef f16 f16x8 __attribute__((ext_vector_type(8)));
typedef float f32x4 __attribute__((ext_vector_type(4)));

// ---------------- weight convert + transpose: fp32 [R][C] -> fp16 [C][R] ----------------
#define TP 66
__global__ __launch_bounds__(256) void cvt_w_t(const float* __restrict__ in,
                                               f16* __restrict__ outp,
                                               int R, int C) {
    __shared__ f16 t[64][TP];
    const float* src = in + (size_t)blockIdx.z * R * C;
    f16* dst = outp + (size_t)blockIdx.z * R * C;
    int r0 = blockIdx.y * 64, c0 = blockIdx.x * 64;
    int tid = threadIdx.x;
    {
        int r = tid >> 4;
        int c = (tid & 15) * 4;
#pragma unroll
        for (int i = 0; i < 4; i++) {
            float4 v = *(const float4*)(src + (size_t)(r0 + r + i * 16) * C + (c0 + c));
            t[r + i * 16][c] = (f16)v.x;
            t[r + i * 16][c + 1] = (f16)v.y;
            t[r + i * 16][c + 2] = (f16)v.z;
            t[r + i * 16][c + 3] = (f16)v.w;
        }
    }
    __syncthreads();
    {
        int c = tid >> 3;
        int rr = (tid & 7) * 8;
#pragma unroll
        for (int i = 0; i < 2; i++) {
            int cc = c + i * 32;
            f16x8 o;
#pragma unroll
            for (int j = 0; j < 8; j++) o[j] = t[rr + j][cc];
            *(f16x8*)(dst + (size_t)(c0 + cc) * R + (r0 + rr)) = o;
        }
    }
}

// ---------------- router ----------------
__global__ __launch_bounds__(256) void router(const float* __restrict__ x,
                                              const float* __restrict__ gw,
                                              const float* __restrict__ gb,
                                              int* __restrict__ counts,
                                              int* __restrict__ list,
                                              float* __restrict__ wslot) {
    int wv = threadIdx.x >> 6;
    int lane = threadIdx.x & 63;
    int tok = blockIdx.x * 4 + wv;
    const float* xr = x + (size_t)tok * D_;
    float acc[E_];
#pragma unroll
    for (int e = 0; e < E_; e++) acc[e] = 0.f;
    for (int d = lane; d < D_; d += 64) {
        float v = xr[d];
        const float* g = gw + d * E_;
#pragma unroll
        for (int e = 0; e < E_; e++) acc[e] += v * g[e];
    }
#pragma unroll
    for (int e = 0; e < E_; e++) {
#pragma unroll
        for (int off = 32; off; off >>= 1) acc[e] += __shfl_xor(acc[e], off, 64);
    }
    if (lane == 0) {
        float v0 = -3.4e38f, v1 = -3.4e38f;
        int i0 = 0, i1 = 0;
#pragma unroll
        for (int e = 0; e < E_; e++) {
            float l = acc[e] + gb[e];
            if (l > v0) { v1 = v0; i1 = i0; v0 = l; i0 = e; }
            else if (l > v1) { v1 = l; i1 = e; }
        }
        float p1 = expf(v1 - v0);
        float s = 1.f + p1;
        int p0 = atomicAdd(&counts[i0], 1);
        list[i0 * N_TOK + p0] = tok * 2;
        int p1p = atomicAdd(&counts[i1], 1);
        list[i1 * N_TOK + p1p] = tok * 2 + 1;
        wslot[tok * 2] = 1.f / s;
        wslot[tok * 2 + 1] = p1 / s;
    }
}

// ---------------- prefix scan over 8 counts ----------------
__global__ void scan8(const int* __restrict__ counts, int* __restrict__ offs) {
    if (threadIdx.x == 0) {
        int s = 0;
#pragma unroll
        for (int e = 0; e < E_; e++) { offs[e] = s; s += counts[e]; }
        offs[E_] = s;
    }
}

// ---------------- pack A: gather token rows -> packed fp16 [8192][D] ----------------
__global__ __launch_bounds__(256) void pack_a(const float* __restrict__ x,
                                              const int* __restrict__ counts,
                                              const int* __restrict__ offs,
                                              const int* __restrict__ list,
                                              f16* __restrict__ xg) {
    int wv = threadIdx.x >> 6, lane = threadIdx.x & 63;
    int idx = blockIdx.x * 4 + wv;            // e*N_TOK + j
    int e = idx >> 12, j = idx & (N_TOK - 1);
    if (j >= counts[e]) return;
    int id = list[idx];
    const float* xr = x + (size_t)(id >> 1) * D_;
    f16* dst = xg + (size_t)(offs[e] + j) * D_;
#pragma unroll
    for (int c = 0; c < 3; c++) {
        float4 v = *(const float4*)(xr + lane * 4 + c * 256);
        f16 o[4] = {(f16)v.x, (f16)v.y, (f16)v.z, (f16)v.w};
        *(float2*)(dst + lane * 4 + c * 256) = *(const float2*)o;
    }
}

// ---------------- shared GEMM machinery (R4 cadence: distance-1, 2-barrier) ----------------
__device__ __forceinline__ void kstep(const f16 A[][PADK], const f16 B[][PADK],
                                      int wr, int wc, int fr, int fk,
                                      f32x4 acc[4][4]) {
    f16x8 af[4], bf[4];
#pragma unroll
    for (int m = 0; m < 4; m++) af[m] = *(const f16x8*)&A[wr + m * 16 + fr][fk];
#pragma unroll
    for (int n = 0; n < 4; n++) bf[n] = *(const f16x8*)&B[wc + n * 16 + fr][fk];
#pragma unroll
    for (int m = 0; m < 4; m++)
#pragma unroll
        for (int n = 0; n < 4; n++)
            acc[m][n] = __builtin_amdgcn_mfma_f32_16x16x32_f16(af[m], bf[n], acc[m][n], 0, 0, 0);
}

#define LOADT(kk) do {                          \
    rA0 = *(const f16x8*)(aptr + (kk));         \
    rA1 = *(const f16x8*)(aptr + (kk) + 8);     \
    rB0 = *(const f16x8*)(bptr + (kk));         \
    rB1 = *(const f16x8*)(bptr + (kk) + 8);     \
} while (0)

#define WRITET() do {                           \
    *(f16x8*)&Alds[sr][sc] = rA0;               \
    *(f16x8*)&Alds[sr][sc + 8] = rA1;           \
    *(f16x8*)&Blds[sr][sc] = rB0;               \
    *(f16x8*)&Blds[sr][sc + 8] = rB1;           \
} while (0)

// ---------------- GEMM1: h = gelu(xg @ w1 + b1), dense packed ----------------
__global__ __launch_bounds__(256) void gemm1(const f16* __restrict__ xg,
                                             const f16* __restrict__ w1t,
                                             const float* __restrict__ b1,
                                             const int* __restrict__ counts,
                                             const int* __restrict__ offs,
                                             f16* __restrict__ hbuf) {
    int e = blockIdx.z;
    int cnt = counts[e];
    int off = offs[e];
    int rb = blockIdx.y * BM;
    if (rb >= cnt) return;
    int cb = blockIdx.x * BN;

    __shared__ f16 Alds[BM][PADK];
    __shared__ f16 Blds[BN][PADK];

    int tid = threadIdx.x;
    int wv = tid >> 6, lane = tid & 63;

    int sr = tid >> 1;             // 0..127
    int sc = (tid & 1) * 16;       // 0 or 16 (two f16x8 chunks)
    int arow = off + rb + sr;
    if (arow > 8191) arow = 8191;  // clamp: rows past segment read valid data, results masked
    const f16* aptr = xg + (size_t)arow * D_ + sc;
    const f16* bptr = w1t + (size_t)e * H_ * D_ + (size_t)(cb + sr) * D_ + sc;

    int wr = (wv >> 1) * 64, wc = (wv & 1) * 64;
    int fr = lane & 15, fk = (lane >> 4) * 8;

    f32x4 acc[4][4] = {};
    f16x8 rA0, rA1, rB0, rB1;

    LOADT(0);
    WRITET();
    __syncthreads();
    const int NT = D_ / BK;  // 24
#pragma unroll 1
    for (int t = 0; t < NT; ++t) {
        bool more = (t + 1 < NT);
        if (more) LOADT((t + 1) * BK);
        kstep(Alds, Blds, wr, wc, fr, fk, acc);
        __syncthreads();
        if (more) WRITET();
        __syncthreads();
    }

#pragma unroll
    for (int n = 0; n < 4; n++) {
        int colg = cb + wc + n * 16 + fr;
        float bias = b1[e * H_ + colg];
#pragma unroll
        for (int m = 0; m < 4; m++) {
#pragma unroll
            for (int r = 0; r < 4; r++) {
                int j = rb + wr + m * 16 + (lane >> 4) * 4 + r;
                if (j < cnt) {
                    float v = acc[m][n][r] + bias;
                    v = 0.5f * v * (1.f + erff(v * 0.70710678f));
                    hbuf[(size_t)(off + j) * H_ + colg] = (f16)v;
                }
            }
        }
    }
}

// ---------------- GEMM2: y = (hbuf @ w2 + b2) * wslot, scatter-add ----------------
#define KSPLIT 2
#define KCH (H_ / KSPLIT)
__global__ __launch_bounds__(256) void gemm2(const f16* __restrict__ hbuf,
                                             const f16* __restrict__ w2t,
                                             const float* __restrict__ b2,
                                             const int* __restrict__ counts,
                                             const int* __restrict__ offs,
                                             const int* __restrict__ list,
                                             const float* __restrict__ wslot,
                                             float* __restrict__ out) {
    int e = blockIdx.z;
    int cnt = counts[e];
    int off = offs[e];
    int rb = blockIdx.y * BM;
    if (rb >= cnt) return;
    int xk = blockIdx.x;                      // 0..11, fastest-varying
    int cb = (xk % (D_ / BN)) * BN;
    int kz = xk / (D_ / BN);
    int k0 = kz * KCH;

    __shared__ f16 Alds[BM][PADK];
    __shared__ f16 Blds[BN][PADK];

    int tid = threadIdx.x;
    int wv = tid >> 6, lane = tid & 63;

    int sr = tid >> 1;
    int sc = (tid & 1) * 16;
    int arow = off + rb + sr;
    if (arow > 8191) arow = 8191;
    const f16* aptr = hbuf + (size_t)arow * H_ + k0 + sc;
    const f16* bptr = w2t + (size_t)e * D_ * H_ + (size_t)(cb + sr) * H_ + k0 + sc;

    int wr = (wv >> 1) * 64, wc = (wv & 1) * 64;
    int fr = lane & 15, fk = (lane >> 4) * 8;

    f32x4 acc[4][4] = {};
    f16x8 rA0, rA1, rB0, rB1;

    LOADT(0);
    WRITET();
    __syncthreads();
    const int NT = KCH / BK;  // 24
#pragma unroll 1
    for (int t = 0; t < NT; ++t) {
        bool more = (t + 1 < NT);
        if (more) LOADT((t + 1) * BK);
        kstep(Alds, Blds, wr, wc, fr, fk, acc);
        __syncthreads();
        if (more) WRITET();
        __syncthreads();
    }

#pragma unroll
    for (int n = 0; n < 4; n++) {
        int colg = cb + wc + n * 16 + fr;
        float bias = (kz == 0) ? b2[e * D_ + colg] : 0.f;
#pragma unroll
        for (int m = 0; m < 4; m++) {
#pragma unroll
            for (int r = 0; r < 4; r++) {
                int j = rb + wr + m * 16 + (lane >> 4) * 4 + r;
                if (j < cnt) {
                    int id = list[e * N_TOK + j];
                    float w = wslot[id];
                    float v = (acc[m][n][r] + bias) * w;
                    atomicAdd(&out[(size_t)(id >> 1) * D_ + colg], v);
                }
            }
        }
    }
}

extern "C" void kernel_launch(void* const* d_in, const int* in_sizes, int n_in,
                              void* d_out, int out_size, void* d_ws, size_t ws_size,
                              hipStream_t stream) {
    const float* x = (const float*)d_in[0];
    const float* gate_w = (const float*)d_in[1];
    const float* gate_b = (const float*)d_in[2];
    const float* w1 = (const float*)d_in[3];
    const float* b1 = (const float*)d_in[4];
    const float* w2 = (const float*)d_in[5];
    const float* b2 = (const float*)d_in[6];
    float* out = (float*)d_out;

    char* ws = (char*)d_ws;
    int* counts = (int*)ws;                           // 32 B
    int* offs = (int*)(ws + 256);                     // 36 B
    int* list = (int*)(ws + 1024);                    // 131072 B
    float* wslot = (float*)(ws + 132096);             // 32768 B
    f16* xg = (f16*)(ws + 196608);                    // 12582912 B
    f16* w1t = (f16*)(ws + 12779520);                 // 37748736 B
    f16* w2t = (f16*)(ws + 50528256);                 // 37748736 B
    f16* hbuf = (f16*)(ws + 88276992);                // 50331648 B

    hipMemsetAsync(counts, 0, 256, stream);
    hipMemsetAsync(out, 0, (size_t)out_size * sizeof(float), stream);

    router<<<1024, 256, 0, stream>>>(x, gate_w, gate_b, counts, list, wslot);
    scan8<<<1, 64, 0, stream>>>(counts, offs);
    pack_a<<<E_ * N_TOK / 4, 256, 0, stream>>>(x, counts, offs, list, xg);
    cvt_w_t<<<dim3(H_ / 64, D_ / 64, E_), 256, 0, stream>>>(w1, w1t, D_, H_);
    cvt_w_t<<<dim3(D_ / 64, H_ / 64, E_), 256, 0, stream>>>(w2, w2t, H_, D_);
    gemm1<<<dim3(H_ / BN, N_TOK / BM, E_), 256, 0, stream>>>(xg, w1t, b1, counts, offs, hbuf);
    gemm2<<<dim3((D_ / BN) * KSPLIT, N_TOK / BM, E_), 256, 0, stream>>>(hbuf, w2t, b2, counts, offs, list, wslot, out);
}

// Round 8
// 336.310 us; speedup vs baseline: 1.4597x; 1.2924x over previous
//
#include <hip/hip_runtime.h>
#include <hip/hip_bf16.h>

#define D_ 768
#define E_ 8
#define H_ 3072
#define N_TOK 4096
#define BT 64
#define BK 64

typedef _Float16 f16;
typedef f16 f16x8 __attribute__((ext_vector_type(8)));
typedef float f32x4 __attribute__((ext_vector_type(4)));

__device__ __forceinline__ void gld16(const f16* g, f16* l) {
    __builtin_amdgcn_global_load_lds(
        (const __attribute__((address_space(1))) unsigned int*)g,
        (__attribute__((address_space(3))) unsigned int*)l, 16, 0, 0);
}

// ---------------- weight convert + transpose + swizzle: fp32 [R][C] -> fp16 [C][R] ----------------
// Output row c is XOR-16B-chunk swizzled: within each 64-half group, chunk k stored at k^(c&7).
#define TP 66
__global__ __launch_bounds__(256) void cvt_w_t(const float* __restrict__ in,
                                               f16* __restrict__ outp,
                                               int R, int C) {
    __shared__ f16 t[64][TP];
    const float* src = in + (size_t)blockIdx.z * R * C;
    f16* dst = outp + (size_t)blockIdx.z * R * C;
    int r0 = blockIdx.y * 64, c0 = blockIdx.x * 64;
    int tid = threadIdx.x;
    {
        int r = tid >> 4;
        int c = (tid & 15) * 4;
#pragma unroll
        for (int i = 0; i < 4; i++) {
            float4 v = *(const float4*)(src + (size_t)(r0 + r + i * 16) * C + (c0 + c));
            t[r + i * 16][c] = (f16)v.x;
            t[r + i * 16][c + 1] = (f16)v.y;
            t[r + i * 16][c + 2] = (f16)v.z;
            t[r + i * 16][c + 3] = (f16)v.w;
        }
    }
    __syncthreads();
    {
        int c = tid >> 3;
        int rr = (tid & 7) * 8;          // chunk-aligned 8-half span along R
        int ch = rr >> 3;                // 0..7 chunk within the 64-half group
#pragma unroll
        for (int i = 0; i < 2; i++) {
            int cc = c + i * 32;
            int rowi = c0 + cc;
            f16x8 o;
#pragma unroll
            for (int j = 0; j < 8; j++) o[j] = t[rr + j][cc];
            *(f16x8*)(dst + (size_t)rowi * R + r0 + (((ch ^ rowi) & 7) << 3)) = o;
        }
    }
}

// ---------------- router ----------------
__global__ __launch_bounds__(256) void router(const float* __restrict__ x,
                                              const float* __restrict__ gw,
                                              const float* __restrict__ gb,
                                              int* __restrict__ counts,
                                              int* __restrict__ list,
                                              float* __restrict__ wslot) {
    int wv = threadIdx.x >> 6;
    int lane = threadIdx.x & 63;
    int tok = blockIdx.x * 4 + wv;
    const float* xr = x + (size_t)tok * D_;
    float acc[E_];
#pragma unroll
    for (int e = 0; e < E_; e++) acc[e] = 0.f;
    for (int d = lane; d < D_; d += 64) {
        float v = xr[d];
        const float* g = gw + d * E_;
#pragma unroll
        for (int e = 0; e < E_; e++) acc[e] += v * g[e];
    }
#pragma unroll
    for (int e = 0; e < E_; e++) {
#pragma unroll
        for (int off = 32; off; off >>= 1) acc[e] += __shfl_xor(acc[e], off, 64);
    }
    if (lane == 0) {
        float v0 = -3.4e38f, v1 = -3.4e38f;
        int i0 = 0, i1 = 0;
#pragma unroll
        for (int e = 0; e < E_; e++) {
            float l = acc[e] + gb[e];
            if (l > v0) { v1 = v0; i1 = i0; v0 = l; i0 = e; }
            else if (l > v1) { v1 = l; i1 = e; }
        }
        float p1 = expf(v1 - v0);
        float s = 1.f + p1;
        int p0 = atomicAdd(&counts[i0], 1);
        list[i0 * N_TOK + p0] = tok * 2;
        int p1p = atomicAdd(&counts[i1], 1);
        list[i1 * N_TOK + p1p] = tok * 2 + 1;
        wslot[tok * 2] = 1.f / s;
        wslot[tok * 2 + 1] = p1 / s;
    }
}

// ---------------- prefix scan over 8 counts ----------------
__global__ void scan8(const int* __restrict__ counts, int* __restrict__ offs) {
    if (threadIdx.x == 0) {
        int s = 0;
#pragma unroll
        for (int e = 0; e < E_; e++) { offs[e] = s; s += counts[e]; }
        offs[E_] = s;
    }
}

// ---------------- pack A: gather token rows -> packed swizzled fp16 [8192][D] ----------------
__global__ __launch_bounds__(256) void pack_a(const float* __restrict__ x,
                                              const int* __restrict__ counts,
                                              const int* __restrict__ offs,
                                              const int* __restrict__ list,
                                              f16* __restrict__ xg) {
    int wv = threadIdx.x >> 6, lane = threadIdx.x & 63;
    int idx = blockIdx.x * 4 + wv;            // e*N_TOK + j
    int e = idx >> 12, j = idx & (N_TOK - 1);
    if (j >= counts[e]) return;
    int id = list[idx];
    int row = offs[e] + j;
    const float* xr = x + (size_t)(id >> 1) * D_;
    f16* dst = xg + (size_t)row * D_;
    int r7 = row & 7;
#pragma unroll
    for (int c = 0; c < 3; c++) {
        int h = lane * 4 + c * 256;
        float4 v = *(const float4*)(xr + h);
        f16 o[4] = {(f16)v.x, (f16)v.y, (f16)v.z, (f16)v.w};
        int hs = (h & ~0x3F) | ((((h >> 3) ^ r7) & 7) << 3) | (h & 7);
        *(float2*)(dst + hs) = *(const float2*)o;
    }
}

// ---------------- GEMM1: h = gelu(xg @ w1 + b1), 64x64 tiles, gld_lds d0 ----------------
__global__ __launch_bounds__(256, 8) void gemm1(const f16* __restrict__ xg,
                                                const f16* __restrict__ w1t,
                                                const float* __restrict__ b1,
                                                const int* __restrict__ counts,
                                                const int* __restrict__ offs,
                                                f16* __restrict__ hbuf) {
    int e = blockIdx.z;
    int cnt = counts[e];
    int off = offs[e];
    int rb = blockIdx.y * BT;
    if (rb >= cnt) return;
    int cb = blockIdx.x * BT;

    __shared__ f16 lds[2 * BT * BK];   // A halfs [0,4096), B halfs [4096,8192)
    char* ldsb = (char*)lds;

    int tid = threadIdx.x;
    int wv = tid >> 6, lane = tid & 63;
    int lr = lane >> 3, lc = lane & 7;

    int r0l = wv * 8 + lr;             // rows 0..31
    int r1l = 32 + wv * 8 + lr;        // rows 32..63
    int ag0 = off + rb + r0l; if (ag0 > 8191) ag0 = 8191;
    int ag1 = off + rb + r1l; if (ag1 > 8191) ag1 = 8191;
    const f16* ap0 = xg + (size_t)ag0 * D_ + lc * 8;
    const f16* ap1 = xg + (size_t)ag1 * D_ + lc * 8;
    const f16* wb = w1t + (size_t)e * H_ * D_;
    const f16* bp0 = wb + (size_t)(cb + r0l) * D_ + lc * 8;
    const f16* bp1 = wb + (size_t)(cb + r1l) * D_ + lc * 8;
    f16* la0 = lds + wv * 512;
    f16* la1 = lds + 2048 + wv * 512;
    f16* lb0 = lds + 4096 + wv * 512;
    f16* lb1 = lds + 6144 + wv * 512;

    int wr = (wv >> 1) * 32, wc = (wv & 1) * 32;
    int fr = lane & 15, qh = lane >> 4;
    int koff = (off + rb) & 7;

    int roA[2][2], roB[2][2];
#pragma unroll
    for (int m = 0; m < 2; m++)
#pragma unroll
        for (int ks = 0; ks < 2; ks++) {
            int row = wr + m * 16 + fr;
            roA[m][ks] = row * 128 + ((((ks * 4 + qh) ^ (koff + row)) & 7) << 4);
            int rwb = wc + m * 16 + fr;
            roB[m][ks] = 8192 + rwb * 128 + ((((ks * 4 + qh) ^ rwb) & 7) << 4);
        }

    f32x4 acc[2][2] = {};
    const int NT = D_ / BK;  // 12
#pragma unroll 1
    for (int t = 0; t < NT; ++t) {
        int kk = t * BK;
        gld16(ap0 + kk, la0);
        gld16(ap1 + kk, la1);
        gld16(bp0 + kk, lb0);
        gld16(bp1 + kk, lb1);
        __syncthreads();
#pragma unroll
        for (int ks = 0; ks < 2; ks++) {
            f16x8 a0 = *(const f16x8*)(ldsb + roA[0][ks]);
            f16x8 a1 = *(const f16x8*)(ldsb + roA[1][ks]);
            f16x8 b0 = *(const f16x8*)(ldsb + roB[0][ks]);
            f16x8 b1v = *(const f16x8*)(ldsb + roB[1][ks]);
            acc[0][0] = __builtin_amdgcn_mfma_f32_16x16x32_f16(a0, b0, acc[0][0], 0, 0, 0);
            acc[0][1] = __builtin_amdgcn_mfma_f32_16x16x32_f16(a0, b1v, acc[0][1], 0, 0, 0);
            acc[1][0] = __builtin_amdgcn_mfma_f32_16x16x32_f16(a1, b0, acc[1][0], 0, 0, 0);
            acc[1][1] = __builtin_amdgcn_mfma_f32_16x16x32_f16(a1, b1v, acc[1][1], 0, 0, 0);
        }
        __syncthreads();
    }

#pragma unroll
    for (int n = 0; n < 2; n++) {
        int colg = cb + wc + n * 16 + fr;
        float bias = b1[e * H_ + colg];
#pragma unroll
        for (int m = 0; m < 2; m++) {
#pragma unroll
            for (int r = 0; r < 4; r++) {
                int j = rb + wr + m * 16 + qh * 4 + r;
                if (j < cnt) {
                    float v = acc[m][n][r] + bias;
                    v = 0.5f * v * (1.f + erff(v * 0.70710678f));
                    int row = off + j;
                    int hs = (colg & ~0x3F) | ((((colg >> 3) ^ row) & 7) << 3) | (colg & 7);
                    hbuf[(size_t)row * H_ + hs] = (f16)v;
                }
            }
        }
    }
}

// ---------------- GEMM2: y = (hbuf @ w2 + b2) * wslot, scatter-add ----------------
#define KSPLIT 2
#define KCH (H_ / KSPLIT)
__global__ __launch_bounds__(256, 8) void gemm2(const f16* __restrict__ hbuf,
                                                const f16* __restrict__ w2t,
                                                const float* __restrict__ b2,
                                                const int* __restrict__ counts,
                                                const int* __restrict__ offs,
                                                const int* __restrict__ list,
                                                const float* __restrict__ wslot,
                                                float* __restrict__ out) {
    int e = blockIdx.z;
    int cnt = counts[e];
    int off = offs[e];
    int rb = blockIdx.y * BT;
    if (rb >= cnt) return;
    int xk = blockIdx.x;                 // 0..23
    int cb = (xk % (D_ / BT)) * BT;
    int kz = xk / (D_ / BT);
    int k0 = kz * KCH;

    __shared__ f16 lds[2 * BT * BK];
    char* ldsb = (char*)lds;

    int tid = threadIdx.x;
    int wv = tid >> 6, lane = tid & 63;
    int lr = lane >> 3, lc = lane & 7;

    int r0l = wv * 8 + lr;
    int r1l = 32 + wv * 8 + lr;
    int ag0 = off + rb + r0l; if (ag0 > 8191) ag0 = 8191;
    int ag1 = off + rb + r1l; if (ag1 > 8191) ag1 = 8191;
    const f16* ap0 = hbuf + (size_t)ag0 * H_ + k0 + lc * 8;
    const f16* ap1 = hbuf + (size_t)ag1 * H_ + k0 + lc * 8;
    const f16* wb = w2t + (size_t)e * D_ * H_;
    const f16* bp0 = wb + (size_t)(cb + r0l) * H_ + k0 + lc * 8;
    const f16* bp1 = wb + (size_t)(cb + r1l) * H_ + k0 + lc * 8;
    f16* la0 = lds + wv * 512;
    f16* la1 = lds + 2048 + wv * 512;
    f16* lb0 = lds + 4096 + wv * 512;
    f16* lb1 = lds + 6144 + wv * 512;

    int wr = (wv >> 1) * 32, wc = (wv & 1) * 32;
    int fr = lane & 15, qh = lane >> 4;
    int koff = (off + rb) & 7;

    int roA[2][2], roB[2][2];
#pragma unroll
    for (int m = 0; m < 2; m++)
#pragma unroll
        for (int ks = 0; ks < 2; ks++) {
            int row = wr + m * 16 + fr;
            roA[m][ks] = row * 128 + ((((ks * 4 + qh) ^ (koff + row)) & 7) << 4);
            int rwb = wc + m * 16 + fr;
            roB[m][ks] = 8192 + rwb * 128 + ((((ks * 4 + qh) ^ rwb) & 7) << 4);
        }

    f32x4 acc[2][2] = {};
    const int NT = KCH / BK;  // 24
#pragma unroll 1
    for (int t = 0; t < NT; ++t) {
        int kk = t * BK;
        gld16(ap0 + kk, la0);
        gld16(ap1 + kk, la1);
        gld16(bp0 + kk, lb0);
        gld16(bp1 + kk, lb1);
        __syncthreads();
#pragma unroll
        for (int ks = 0; ks < 2; ks++) {
            f16x8 a0 = *(const f16x8*)(ldsb + roA[0][ks]);
            f16x8 a1 = *(const f16x8*)(ldsb + roA[1][ks]);
            f16x8 b0 = *(const f16x8*)(ldsb + roB[0][ks]);
            f16x8 b1v = *(const f16x8*)(ldsb + roB[1][ks]);
            acc[0][0] = __builtin_amdgcn_mfma_f32_16x16x32_f16(a0, b0, acc[0][0], 0, 0, 0);
            acc[0][1] = __builtin_amdgcn_mfma_f32_16x16x32_f16(a0, b1v, acc[0][1], 0, 0, 0);
            acc[1][0] = __builtin_amdgcn_mfma_f32_16x16x32_f16(a1, b0, acc[1][0], 0, 0, 0);
            acc[1][1] = __builtin_amdgcn_mfma_f32_16x16x32_f16(a1, b1v, acc[1][1], 0, 0, 0);
        }
        __syncthreads();
    }

#pragma unroll
    for (int n = 0; n < 2; n++) {
        int colg = cb + wc + n * 16 + fr;
        float bias = (kz == 0) ? b2[e * D_ + colg] : 0.f;
#pragma unroll
        for (int m = 0; m < 2; m++) {
#pragma unroll
            for (int r = 0; r < 4; r++) {
                int j = rb + wr + m * 16 + qh * 4 + r;
                if (j < cnt) {
                    int id = list[e * N_TOK + j];
                    float w = wslot[id];
                    float v = (acc[m][n][r] + bias) * w;
                    atomicAdd(&out[(size_t)(id >> 1) * D_ + colg], v);
                }
            }
        }
    }
}

extern "C" void kernel_launch(void* const* d_in, const int* in_sizes, int n_in,
                              void* d_out, int out_size, void* d_ws, size_t ws_size,
                              hipStream_t stream) {
    const float* x = (const float*)d_in[0];
    const float* gate_w = (const float*)d_in[1];
    const float* gate_b = (const float*)d_in[2];
    const float* w1 = (const float*)d_in[3];
    const float* b1 = (const float*)d_in[4];
    const float* w2 = (const float*)d_in[5];
    const float* b2 = (const float*)d_in[6];
    float* out = (float*)d_out;

    char* ws = (char*)d_ws;
    int* counts = (int*)ws;                           // 32 B
    int* offs = (int*)(ws + 256);                     // 36 B
    int* list = (int*)(ws + 1024);                    // 131072 B
    float* wslot = (float*)(ws + 132096);             // 32768 B
    f16* xg = (f16*)(ws + 196608);                    // 12582912 B
    f16* w1t = (f16*)(ws + 12779520);                 // 37748736 B
    f16* w2t = (f16*)(ws + 50528256);                 // 37748736 B
    f16* hbuf = (f16*)(ws + 88276992);                // 50331648 B

    hipMemsetAsync(counts, 0, 256, stream);
    hipMemsetAsync(out, 0, (size_t)out_size * sizeof(float), stream);

    router<<<1024, 256, 0, stream>>>(x, gate_w, gate_b, counts, list, wslot);
    scan8<<<1, 64, 0, stream>>>(counts, offs);
    pack_a<<<E_ * N_TOK / 4, 256, 0, stream>>>(x, counts, offs, list, xg);
    cvt_w_t<<<dim3(H_ / 64, D_ / 64, E_), 256, 0, stream>>>(w1, w1t, D_, H_);
    cvt_w_t<<<dim3(D_ / 64, H_ / 64, E_), 256, 0, stream>>>(w2, w2t, H_, D_);
    gemm1<<<dim3(H_ / BT, N_TOK / BT, E_), 256, 0, stream>>>(xg, w1t, b1, counts, offs, hbuf);
    gemm2<<<dim3((D_ / BT) * KSPLIT, N_TOK / BT, E_), 256, 0, stream>>>(hbuf, w2t, b2, counts, offs, list, wslot, out);
}